// Round 1
// baseline (392.037 us; speedup 1.0000x reference)
//
#include <hip/hip_runtime.h>

// LIF bitshift-decay scan: B=32, T=1024, N=1024, n_syn=2.
// One thread per (b, n) scan; 512 blocks x 64 threads = 32768 threads = 2 waves/CU.
// Latency hiding: 16-step register double-buffer prefetch (32 outstanding dword
// loads/thread while computing the previous chunk).
//
// Numerics: must be bit-exact vs numpy fp32 reference (spike threshold is a hard
// discontinuity). All decay factors are powers of two (exact multiplies), and the
// add order below matches the reference exactly:
//   isyn = (isyn - isyn*sd) + x
//   vmem = (vmem - vmem*md) + (i0 + i1)

#define TT 1024
#define NN 1024
#define BB 32
#define UU 16   // time-steps per prefetch chunk

__global__ __launch_bounds__(64, 1)
void lif_scan_kernel(const float* __restrict__ in, float* __restrict__ out) {
    const int gid = blockIdx.x * 64 + threadIdx.x;   // 0 .. 32767
    const int b = gid >> 10;                          // / NN
    const int n = gid & (NN - 1);

    // input layout:  ((b*T + t)*2 + s)*N + n  -> ip + t*2048 + s*1024
    const float* __restrict__ ip = in + (size_t)b * TT * 2 * NN + n;
    // output layout: (b*T + t)*N + n          -> op + t*1024
    float* __restrict__ op = out + (size_t)b * TT * NN + n;

    const float SD0 = 0.25f;   // 2^-2  (tau_syn=5 -> dash 2)
    const float SD1 = 0.5f;    // 2^-1  (tau_syn=2 -> dash 1)
    const float MD  = 0.125f;  // 2^-3  (tau_mem=10 -> dash 3)

    float i0 = 0.0f, i1 = 0.0f, v = 0.0f;

    // prefetch chunk 0
    float x0[UU], x1[UU];
#pragma unroll
    for (int j = 0; j < UU; ++j) {
        x0[j] = ip[j * 2048];
        x1[j] = ip[j * 2048 + 1024];
    }

    // main loop: prefetch chunk k+1 while computing chunk k
    for (int tc = 0; tc < TT - UU; tc += UU) {
        float y0[UU], y1[UU];
        const float* pn = ip + (tc + UU) * 2048;
#pragma unroll
        for (int j = 0; j < UU; ++j) {
            y0[j] = pn[j * 2048];
            y1[j] = pn[j * 2048 + 1024];
        }
        float* po = op + tc * NN;
#pragma unroll
        for (int j = 0; j < UU; ++j) {
            i0 = (i0 - i0 * SD0) + x0[j];
            i1 = (i1 - i1 * SD1) + x1[j];
            float vd = v - v * MD;
            v = vd + (i0 + i1);
            float spk = (v >= 1.0f) ? 1.0f : 0.0f;
            v -= spk;                      // membrane-subtract reset (thr = 1.0)
            po[j * NN] = spk;
        }
#pragma unroll
        for (int j = 0; j < UU; ++j) { x0[j] = y0[j]; x1[j] = y1[j]; }
    }

    // epilogue: last chunk (no prefetch)
    {
        float* po = op + (TT - UU) * NN;
#pragma unroll
        for (int j = 0; j < UU; ++j) {
            i0 = (i0 - i0 * SD0) + x0[j];
            i1 = (i1 - i1 * SD1) + x1[j];
            float vd = v - v * MD;
            v = vd + (i0 + i1);
            float spk = (v >= 1.0f) ? 1.0f : 0.0f;
            v -= spk;
            po[j * NN] = spk;
        }
    }
}

extern "C" void kernel_launch(void* const* d_in, const int* in_sizes, int n_in,
                              void* d_out, int out_size, void* d_ws, size_t ws_size,
                              hipStream_t stream) {
    const float* in = (const float*)d_in[0];
    float* out = (float*)d_out;
    dim3 grid(BB * NN / 64);   // 512 blocks -> ~2 blocks/CU on 256 CUs
    dim3 block(64);            // one wave per block
    hipLaunchKernelGGL(lif_scan_kernel, grid, block, 0, stream, in, out);
}